// Round 8
// baseline (135.905 us; speedup 1.0000x reference)
//
#include <hip/hip_runtime.h>

// StructuredStateSpace: h_t = A h_{t-1} + Bw x_t + Bb ; y_t = Cw h_t
// B=16, S=8192, D_IN=64, D_ST=128.  All operands f16 hi+lo pairs, 3 of 4
// cross terms (validated r3/r4/r7: absmax 0.156).
//
// Round-8: exact two-kernel chunked scan, NO warm-up. LCH=16, 512 chunks.
//   scan1: per chunk, run the validated r4 step loop from h=0 (no emit),
//          store end-state v_c (hi/lo B-frag layout) to ws.
//   scan2: h_start(c) = sum_{k=1..7} T^{k-1} v_{c-k}  (T = A^16; truncation
//          ||A^112|| = the validated WTOT=112 horizon), via MFMA with
//          rho-packed hi/lo {I, A16, A32, A48, A64, A80, A96}; then the r4
//          output loop (16 steps, emit).
// Prep: 7 small fp32 128x128x128 matmul launches (power chain) + 1 pack.

#define SEQ   8192
#define DIN   64
#define LCH   16
#define NCH   (SEQ / LCH)        // 512 chunks -> 2 blocks/CU
#define KCOMB 7

typedef _Float16 v8h __attribute__((ext_vector_type(8)));
typedef __fp16   v2h __attribute__((ext_vector_type(2)));
typedef float    v4f __attribute__((ext_vector_type(4)));

#define MFMA(a, b, c) __builtin_amdgcn_mfma_f32_16x16x32_f16((a), (b), (c), 0, 0, 0)
#define PKRTZ __builtin_amdgcn_cvt_pkrtz
#define Z4 (v4f{0.f, 0.f, 0.f, 0.f})

// F (f16 element offsets): Ah 0 | Al 16384 | Bwh 32768 | Bwl 40960 |
// Cwh 49152 | Cwl 57344 | Th[k] 65536+k*16384 (k=0..6) | Tl[k] 180224+k*16384
// F end = 294912 f16 = 589824 B.
// f32: Bbs @ byte 589824 (128 f32); pw @ byte 590336: 9 slots of 16384 f32
//   (A2,A4,A8,A16,A32,A48,A64,A80,A96).
// Vbuf (f16) @ byte 1180160: [512 chunks][4096] (hi 2048 | lo 2048).
// Total ws = 5374464 bytes.

__device__ __forceinline__ int rho_fwd(int lidx) {
  int kt = lidx >> 5, q = (lidx >> 3) & 3, e = lidx & 7;
  int eh = e >> 1;
  int m = kt + 4 * (eh & 1);
  int r = 2 * (eh >> 1) + (e & 1);
  return 16 * m + 4 * q + r;
}
__device__ __forceinline__ int rho_inv(int p) {
  int m = p >> 4, q = (p >> 2) & 3, r = p & 3;
  int eh = ((r >> 1) << 1) | (m >> 2);
  int e  = (eh << 1) | (r & 1);
  return 32 * (m & 3) + 8 * q + e;
}
__device__ __forceinline__ void pack_hl(float v, _Float16* hp, _Float16* lp) {
  _Float16 h = (_Float16)v;
  *hp = h; *lp = (_Float16)(v - (float)h);
}

// up to 3 fp32 128x128 matmuls per launch; blockIdx.x>>6 selects.
__global__ void mmk(const float* x0, const float* y0, float* d0,
                    const float* x1, const float* y1, float* d1,
                    const float* x2, const float* y2, float* d2) {
  int which = blockIdx.x >> 6;
  const float* X = (which == 0) ? x0 : ((which == 1) ? x1 : x2);
  const float* Y = (which == 0) ? y0 : ((which == 1) ? y1 : y2);
  float*       D = (which == 0) ? d0 : ((which == 1) ? d1 : d2);
  int idx = (blockIdx.x & 63) * 256 + threadIdx.x;
  int i = idx >> 7, j = idx & 127;
  float s = 0.f;
  for (int k = 0; k < 128; ++k) s = fmaf(X[i * 128 + k], Y[k * 128 + j], s);
  D[idx] = s;
}

__global__ void packk(const float* __restrict__ A, const float* __restrict__ Bw,
                      const float* __restrict__ Bb, const float* __restrict__ Cw,
                      const float* __restrict__ pw, _Float16* __restrict__ F,
                      float* __restrict__ Bbs) {
  int idx = blockIdx.x * 256 + threadIdx.x;
  if (idx < 16384) {                       // A, rho rows
    int i = idx >> 7, j = idx & 127;
    int o = rho_fwd(i) * 128 + j;
    pack_hl(A[idx], F + o, F + 16384 + o);
  } else if (idx < 24576) {                // Bw, rho rows
    int p = idx - 16384; int i = p >> 6, j = p & 63;
    int o = rho_fwd(i) * 64 + j;
    pack_hl(Bw[p], F + 32768 + o, F + 40960 + o);
  } else if (idx < 32768) {                // Cw plain
    int p = idx - 24576;
    pack_hl(Cw[p], F + 49152 + p, F + 57344 + p);
  } else if (idx < 32896) {                // Bbs rho
    int i = idx - 32768;
    Bbs[i] = Bb[rho_inv(i)];
  } else if (idx < 147584) {               // T slots k=0..6: I, A16..A96 (rho rows)
    int p = idx - 32896;
    int k = p >> 14, r = p & 16383;
    int i = r >> 7, j = r & 127;
    float v = (k == 0) ? ((i == j) ? 1.f : 0.f) : pw[(k + 2) * 16384 + r];
    int o = rho_fwd(i) * 128 + j;
    pack_hl(v, F + 65536 + k * 16384 + o, F + 180224 + k * 16384 + o);
  }
}

__device__ __forceinline__ void split16(const v4f* b, v8h& xh0, v8h& xh1,
                                        v8h& xl0, v8h& xl1) {
  union { v2h h2[4]; v8h h8; } H0, H1;
  H0.h2[0] = PKRTZ(b[0][0], b[0][1]); H0.h2[1] = PKRTZ(b[0][2], b[0][3]);
  H0.h2[2] = PKRTZ(b[1][0], b[1][1]); H0.h2[3] = PKRTZ(b[1][2], b[1][3]);
  H1.h2[0] = PKRTZ(b[2][0], b[2][1]); H1.h2[1] = PKRTZ(b[2][2], b[2][3]);
  H1.h2[2] = PKRTZ(b[3][0], b[3][1]); H1.h2[3] = PKRTZ(b[3][2], b[3][3]);
  float r[16];
#pragma unroll
  for (int i = 0; i < 8; ++i) r[i]     = b[i >> 2][i & 3]       - (float)H0.h8[i];
#pragma unroll
  for (int i = 0; i < 8; ++i) r[8 + i] = b[2 + (i >> 2)][i & 3] - (float)H1.h8[i];
  union { v2h h2[4]; v8h h8; } L0, L1;
  L0.h2[0] = PKRTZ(r[0], r[1]);   L0.h2[1] = PKRTZ(r[2], r[3]);
  L0.h2[2] = PKRTZ(r[4], r[5]);   L0.h2[3] = PKRTZ(r[6], r[7]);
  L1.h2[0] = PKRTZ(r[8], r[9]);   L1.h2[1] = PKRTZ(r[10], r[11]);
  L1.h2[2] = PKRTZ(r[12], r[13]); L1.h2[3] = PKRTZ(r[14], r[15]);
  xh0 = H0.h8; xh1 = H1.h8; xl0 = L0.h8; xl1 = L1.h8;
}

// ---------------- scan1: local chunk scan from h=0, store v_c ----------------
__global__ __launch_bounds__(256, 2) void scan1(
    const float* __restrict__ x, const _Float16* __restrict__ F,
    const float* __restrict__ Bbs, _Float16* __restrict__ Vbuf) {
  const int tid = threadIdx.x;
  const int wv  = tid >> 6;
  const int l   = tid & 63;
  const int n   = l & 15;
  const int q   = l >> 4;
  const int c   = blockIdx.x;
  const int t0  = c * LCH, te = t0 + LCH;

  const _Float16* Ah = F;
  const _Float16* Al = F + 16384;
  const _Float16* Bh = F + 32768;
  const _Float16* Bl = F + 40960;

  v8h afh[2][4], afl[2][4], bwh[2][2], bwl[2][2];
  v4f bb2[2];
#pragma unroll
  for (int i = 0; i < 2; ++i) {
    int row = 16 * (wv + 4 * i) + n;
#pragma unroll
    for (int kt = 0; kt < 4; ++kt) {
      afh[i][kt] = *(const v8h*)(Ah + row * 128 + 32 * kt + 8 * q);
      afl[i][kt] = *(const v8h*)(Al + row * 128 + 32 * kt + 8 * q);
    }
#pragma unroll
    for (int k2 = 0; k2 < 2; ++k2) {
      bwh[i][k2] = *(const v8h*)(Bh + row * 64 + 32 * k2 + 8 * q);
      bwl[i][k2] = *(const v8h*)(Bl + row * 64 + 32 * k2 + 8 * q);
    }
    bb2[i] = *(const v4f*)(Bbs + 16 * (wv + 4 * i) + 4 * q);
  }

  __shared__ _Float16 hx[2][2][4][512];

  const float* xb = x + (size_t)n * (SEQ * DIN) + 8 * q;
  v4f bufA[4], bufB[4], uA[2], uB[2];
  auto loadx = [&](v4f(&buf)[4], int t) {
    const float* p = xb + (size_t)t * DIN;
    buf[0] = *(const v4f*)(p);     buf[1] = *(const v4f*)(p + 4);
    buf[2] = *(const v4f*)(p + 32); buf[3] = *(const v4f*)(p + 36);
  };
  auto build_u = [&](const v4f(&b)[4]) {
    v8h xh0, xh1, xl0, xl1;
    split16(b, xh0, xh1, xl0, xl1);
#pragma unroll
    for (int i = 0; i < 2; ++i) {
      v4f a = bb2[i];
      a = MFMA(bwh[i][0], xh0, a);
      a = MFMA(bwh[i][1], xh1, a);
      uA[i] = a;
      v4f b1 = MFMA(bwl[i][0], xh0, Z4);
      b1 = MFMA(bwl[i][1], xh1, b1);
      v4f b2 = MFMA(bwh[i][0], xl0, Z4);
      b2 = MFMA(bwh[i][1], xl1, b2);
      uB[i] = b1 + b2;
    }
  };
  auto xwrite = [&](int pr, const v4f& a0, const v4f& a1) {
    union { v2h h2[4]; v8h h8; } U;
    U.h2[0] = PKRTZ(a0[0], a0[1]); U.h2[1] = PKRTZ(a1[0], a1[1]);
    U.h2[2] = PKRTZ(a0[2], a0[3]); U.h2[3] = PKRTZ(a1[2], a1[3]);
    *(v8h*)&hx[pr][0][wv][l * 8] = U.h8;
    float r0 = a0[0] - (float)U.h8[0], r1 = a0[1] - (float)U.h8[1];
    float r2 = a1[0] - (float)U.h8[2], r3 = a1[1] - (float)U.h8[3];
    float r4 = a0[2] - (float)U.h8[4], r5 = a0[3] - (float)U.h8[5];
    float r6 = a1[2] - (float)U.h8[6], r7 = a1[3] - (float)U.h8[7];
    union { v2h h2[4]; v8h h8; } L;
    L.h2[0] = PKRTZ(r0, r1); L.h2[1] = PKRTZ(r2, r3);
    L.h2[2] = PKRTZ(r4, r5); L.h2[3] = PKRTZ(r6, r7);
    *(v8h*)&hx[pr][1][wv][l * 8] = L.h8;
  };

  v8h hf[4], hlo[4];
#pragma unroll
  for (int kt = 0; kt < 4; ++kt) { hf[kt] = v8h{}; hlo[kt] = v8h{}; }

  auto step_full = [&](int t, v4f(&bsrc)[4], v4f(&bld)[4], int pr) {
    v4f acc[2];
#pragma unroll
    for (int i = 0; i < 2; ++i) {
      v4f a = MFMA(afh[i][0], hf[0], uA[i]);
      a     = MFMA(afh[i][1], hf[1], a);
      v4f b = MFMA(afh[i][2], hf[2], Z4);
      b     = MFMA(afh[i][3], hf[3], b);
      v4f c2a = MFMA(afl[i][0], hf[0], uB[i]);
      c2a     = MFMA(afl[i][1], hf[1], c2a);
      v4f c2b = MFMA(afl[i][2], hf[2], Z4);
      c2b     = MFMA(afl[i][3], hf[3], c2b);
      v4f c3a = MFMA(afh[i][0], hlo[0], Z4);
      c3a     = MFMA(afh[i][1], hlo[1], c3a);
      v4f c3b = MFMA(afh[i][2], hlo[2], Z4);
      c3b     = MFMA(afh[i][3], hlo[3], c3b);
      acc[i] = (a + b) + (c2a + c2b) + (c3a + c3b);
    }
    build_u(bsrc);
    int tn = t + 2; if (tn > SEQ - 1) tn = SEQ - 1;
    loadx(bld, tn);
    xwrite(pr, acc[0], acc[1]);
    __syncthreads();
#pragma unroll
    for (int kt = 0; kt < 4; ++kt) {
      hf[kt]  = *(const v8h*)&hx[pr][0][kt][l * 8];
      hlo[kt] = *(const v8h*)&hx[pr][1][kt][l * 8];
    }
  };

  loadx(bufA, t0);
  loadx(bufB, t0 + 1);
  build_u(bufA);
  for (int t = t0; t < te; t += 2) {
    step_full(t,     bufB, bufA, 0);
    step_full(t + 1, bufA, bufB, 1);
  }
  // store v_c: LDS hx[1] holds the end state (hi then lo), 256 v8h each
  const v8h* sh = (const v8h*)&hx[1][0][0][0];
  const v8h* sl = (const v8h*)&hx[1][1][0][0];
  v8h* vb = (v8h*)(Vbuf + (size_t)c * 4096);
  vb[tid] = sh[tid];
  vb[256 + tid] = sl[tid];
}

// -------- scan2: combine h_start from v_{c-1..c-7}, then emit 16 steps -------
__global__ __launch_bounds__(256, 2) void scan2(
    const float* __restrict__ x, float* __restrict__ y,
    const _Float16* __restrict__ F, const float* __restrict__ Bbs,
    const _Float16* __restrict__ Vbuf) {
  const int tid = threadIdx.x;
  const int wv  = tid >> 6;
  const int l   = tid & 63;
  const int n   = l & 15;
  const int q   = l >> 4;
  const int c   = blockIdx.x;
  const int t0  = c * LCH, te = t0 + LCH;

  const _Float16* Ah = F;
  const _Float16* Al = F + 16384;
  const _Float16* Bh = F + 32768;
  const _Float16* Bl = F + 40960;
  const _Float16* Ch = F + 49152;
  const _Float16* Cl = F + 57344;

  v8h afh[2][4], afl[2][4], bwh[2][2], bwl[2][2], cwh[4], cwl[4];
  v4f bb2[2];
#pragma unroll
  for (int i = 0; i < 2; ++i) {
    int row = 16 * (wv + 4 * i) + n;
#pragma unroll
    for (int kt = 0; kt < 4; ++kt) {
      afh[i][kt] = *(const v8h*)(Ah + row * 128 + 32 * kt + 8 * q);
      afl[i][kt] = *(const v8h*)(Al + row * 128 + 32 * kt + 8 * q);
    }
#pragma unroll
    for (int k2 = 0; k2 < 2; ++k2) {
      bwh[i][k2] = *(const v8h*)(Bh + row * 64 + 32 * k2 + 8 * q);
      bwl[i][k2] = *(const v8h*)(Bl + row * 64 + 32 * k2 + 8 * q);
    }
    bb2[i] = *(const v4f*)(Bbs + 16 * (wv + 4 * i) + 4 * q);
  }
  {
    int row = 16 * wv + n;
#pragma unroll
    for (int kt = 0; kt < 4; ++kt) {
      cwh[kt] = *(const v8h*)(Ch + row * 128 + 32 * kt + 8 * q);
      cwl[kt] = *(const v8h*)(Cl + row * 128 + 32 * kt + 8 * q);
    }
  }

  __shared__ _Float16 hx[2][2][4][512];

  v8h hf[4], hlo[4];
#pragma unroll
  for (int kt = 0; kt < 4; ++kt) { hf[kt] = v8h{}; hlo[kt] = v8h{}; }

  auto xwrite = [&](int pr, const v4f& a0, const v4f& a1) {
    union { v2h h2[4]; v8h h8; } U;
    U.h2[0] = PKRTZ(a0[0], a0[1]); U.h2[1] = PKRTZ(a1[0], a1[1]);
    U.h2[2] = PKRTZ(a0[2], a0[3]); U.h2[3] = PKRTZ(a1[2], a1[3]);
    *(v8h*)&hx[pr][0][wv][l * 8] = U.h8;
    float r0 = a0[0] - (float)U.h8[0], r1 = a0[1] - (float)U.h8[1];
    float r2 = a1[0] - (float)U.h8[2], r3 = a1[1] - (float)U.h8[3];
    float r4 = a0[2] - (float)U.h8[4], r5 = a0[3] - (float)U.h8[5];
    float r6 = a1[2] - (float)U.h8[6], r7 = a1[3] - (float)U.h8[7];
    union { v2h h2[4]; v8h h8; } L;
    L.h2[0] = PKRTZ(r0, r1); L.h2[1] = PKRTZ(r2, r3);
    L.h2[2] = PKRTZ(r4, r5); L.h2[3] = PKRTZ(r6, r7);
    *(v8h*)&hx[pr][1][wv][l * 8] = L.h8;
  };

  // ---- combine: h_start = sum_{k=1..min(7,c)} T^{k-1} v_{c-k} (pr=1 xchg)
  if (c > 0) {
    const int kmax = (c < KCOMB) ? c : KCOMB;
    v4f c1[2] = {Z4, Z4}, c2[2] = {Z4, Z4}, c3[2] = {Z4, Z4};
    for (int k = 1; k <= kmax; ++k) {
      const v8h* vb = (const v8h*)(Vbuf + (size_t)(c - k) * 4096);
      v8h vh[4], vl[4];
#pragma unroll
      for (int kt = 0; kt < 4; ++kt) {
        vh[kt] = vb[kt * 64 + l];
        vl[kt] = vb[256 + kt * 64 + l];
      }
      const _Float16* th = F + 65536  + (k - 1) * 16384;
      const _Float16* tl = F + 180224 + (k - 1) * 16384;
#pragma unroll
      for (int i = 0; i < 2; ++i) {
        int row = 16 * (wv + 4 * i) + n;
#pragma unroll
        for (int kt = 0; kt < 4; ++kt) {
          v8h tfh = *(const v8h*)(th + row * 128 + 32 * kt + 8 * q);
          v8h tfl = *(const v8h*)(tl + row * 128 + 32 * kt + 8 * q);
          c1[i] = MFMA(tfh, vh[kt], c1[i]);
          c2[i] = MFMA(tfl, vh[kt], c2[i]);
          c3[i] = MFMA(tfh, vl[kt], c3[i]);
        }
      }
    }
    v4f a0 = c1[0] + c2[0] + c3[0];
    v4f a1 = c1[1] + c2[1] + c3[1];
    xwrite(1, a0, a1);
    __syncthreads();
#pragma unroll
    for (int kt = 0; kt < 4; ++kt) {
      hf[kt]  = *(const v8h*)&hx[1][0][kt][l * 8];
      hlo[kt] = *(const v8h*)&hx[1][1][kt][l * 8];
    }
  }

  const float* xb = x + (size_t)n * (SEQ * DIN) + 8 * q;
  float* yb = y + (size_t)n * (SEQ * DIN);
  v4f bufA[4], bufB[4], uA[2], uB[2];
  auto loadx = [&](v4f(&buf)[4], int t) {
    const float* p = xb + (size_t)t * DIN;
    buf[0] = *(const v4f*)(p);      buf[1] = *(const v4f*)(p + 4);
    buf[2] = *(const v4f*)(p + 32); buf[3] = *(const v4f*)(p + 36);
  };
  auto build_u = [&](const v4f(&b)[4]) {
    v8h xh0, xh1, xl0, xl1;
    split16(b, xh0, xh1, xl0, xl1);
#pragma unroll
    for (int i = 0; i < 2; ++i) {
      v4f a = bb2[i];
      a = MFMA(bwh[i][0], xh0, a);
      a = MFMA(bwh[i][1], xh1, a);
      uA[i] = a;
      v4f b1 = MFMA(bwl[i][0], xh0, Z4);
      b1 = MFMA(bwl[i][1], xh1, b1);
      v4f b2 = MFMA(bwh[i][0], xl0, Z4);
      b2 = MFMA(bwh[i][1], xl1, b2);
      uB[i] = b1 + b2;
    }
  };
  auto emit_y = [&](int t) {
    v4f e1a = MFMA(cwh[1], hf[1], MFMA(cwh[0], hf[0], Z4));
    v4f e1b = MFMA(cwh[3], hf[3], MFMA(cwh[2], hf[2], Z4));
    v4f e2a = MFMA(cwh[1], hlo[1], MFMA(cwh[0], hlo[0], Z4));
    v4f e2b = MFMA(cwh[3], hlo[3], MFMA(cwh[2], hlo[2], Z4));
    v4f e3a = MFMA(cwl[1], hf[1], MFMA(cwl[0], hf[0], Z4));
    v4f e3b = MFMA(cwl[3], hf[3], MFMA(cwl[2], hf[2], Z4));
    v4f r = (e1a + e1b) + (e2a + e2b) + (e3a + e3b);
    *(v4f*)(yb + (size_t)t * DIN + 16 * wv + 4 * q) = r;
  };
  auto step_full = [&](int t, v4f(&bsrc)[4], v4f(&bld)[4], int pr, bool emit) {
    if (emit) emit_y(t - 1);
    v4f acc[2];
#pragma unroll
    for (int i = 0; i < 2; ++i) {
      v4f a = MFMA(afh[i][0], hf[0], uA[i]);
      a     = MFMA(afh[i][1], hf[1], a);
      v4f b = MFMA(afh[i][2], hf[2], Z4);
      b     = MFMA(afh[i][3], hf[3], b);
      v4f c2a = MFMA(afl[i][0], hf[0], uB[i]);
      c2a     = MFMA(afl[i][1], hf[1], c2a);
      v4f c2b = MFMA(afl[i][2], hf[2], Z4);
      c2b     = MFMA(afl[i][3], hf[3], c2b);
      v4f c3a = MFMA(afh[i][0], hlo[0], Z4);
      c3a     = MFMA(afh[i][1], hlo[1], c3a);
      v4f c3b = MFMA(afh[i][2], hlo[2], Z4);
      c3b     = MFMA(afh[i][3], hlo[3], c3b);
      acc[i] = (a + b) + (c2a + c2b) + (c3a + c3b);
    }
    build_u(bsrc);
    int tn = t + 2; if (tn > SEQ - 1) tn = SEQ - 1;
    loadx(bld, tn);
    xwrite(pr, acc[0], acc[1]);
    __syncthreads();
#pragma unroll
    for (int kt = 0; kt < 4; ++kt) {
      hf[kt]  = *(const v8h*)&hx[pr][0][kt][l * 8];
      hlo[kt] = *(const v8h*)&hx[pr][1][kt][l * 8];
    }
  };

  loadx(bufA, t0);
  loadx(bufB, t0 + 1);
  build_u(bufA);
  for (int t = t0; t < te; t += 2) {
    step_full(t,     bufB, bufA, 0, t > t0);
    step_full(t + 1, bufA, bufB, 1, true);
  }
  emit_y(te - 1);
}

extern "C" void kernel_launch(void* const* d_in, const int* in_sizes, int n_in,
                              void* d_out, int out_size, void* d_ws, size_t ws_size,
                              hipStream_t stream) {
  const float* x  = (const float*)d_in[0];
  const float* A  = (const float*)d_in[1];
  const float* Bw = (const float*)d_in[2];
  const float* Bb = (const float*)d_in[3];
  const float* Cw = (const float*)d_in[4];
  float* y = (float*)d_out;

  _Float16* F    = (_Float16*)d_ws;                       // 589824 B
  float*    Bbs  = (float*)((char*)d_ws + 589824);        // 512 B
  float*    pw   = (float*)((char*)d_ws + 590336);        // 9*65536 B
  _Float16* Vbuf = (_Float16*)((char*)d_ws + 1180160);    // 4 MiB  (total 5374464 B)

  float* A2  = pw;
  float* A4  = pw + 1 * 16384;
  float* A8  = pw + 2 * 16384;
  float* A16 = pw + 3 * 16384;
  float* A32 = pw + 4 * 16384;
  float* A48 = pw + 5 * 16384;
  float* A64 = pw + 6 * 16384;
  float* A80 = pw + 7 * 16384;
  float* A96 = pw + 8 * 16384;

  mmk<<<64,  256, 0, stream>>>(A,   A,   A2,  nullptr, nullptr, nullptr, nullptr, nullptr, nullptr);
  mmk<<<64,  256, 0, stream>>>(A2,  A2,  A4,  nullptr, nullptr, nullptr, nullptr, nullptr, nullptr);
  mmk<<<64,  256, 0, stream>>>(A4,  A4,  A8,  nullptr, nullptr, nullptr, nullptr, nullptr, nullptr);
  mmk<<<64,  256, 0, stream>>>(A8,  A8,  A16, nullptr, nullptr, nullptr, nullptr, nullptr, nullptr);
  mmk<<<64,  256, 0, stream>>>(A16, A16, A32, nullptr, nullptr, nullptr, nullptr, nullptr, nullptr);
  mmk<<<128, 256, 0, stream>>>(A32, A16, A48, A32, A32, A64, nullptr, nullptr, nullptr);
  mmk<<<128, 256, 0, stream>>>(A64, A16, A80, A64, A32, A96, nullptr, nullptr, nullptr);
  packk<<<577, 256, 0, stream>>>(A, Bw, Bb, Cw, pw, F, Bbs);
  scan1<<<NCH, 256, 0, stream>>>(x, F, Bbs, Vbuf);
  scan2<<<NCH, 256, 0, stream>>>(x, y, F, Bbs, Vbuf);
}

// Round 9
// 93.582 us; speedup vs baseline: 1.4523x; 1.4523x over previous
//
#include <hip/hip_runtime.h>

// StructuredStateSpace: h_t = A h_{t-1} + Bw x_t + Bb ; y_t = Cw h_t
// B=16, S=8192, D_IN=64, D_ST=128.  All operands f16 hi+lo pairs, 3 of 4
// cross terms (validated r3/r4/r7/r8: absmax 0.156-0.1875).
//
// Round-9: exact two-kernel chunked scan (r8) with three fixes:
//  (1) per-step x prefetch issued FIRST in the step body -- __syncthreads
//      emits s_waitcnt vmcnt(0), so a load issued just before the barrier
//      serializes its full HBM latency into every step (r8's ~2000cyc/step).
//  (2) Horner combine: h_start(c) = v_{c-1} + T(v_{c-2} + T(...)), T=A^16
//      only -> power chain 7 -> 4 launches, 1 packed T instead of 7.
//      Each Horner level reuses the validated step primitive with u := v.
//  (3) v_c stored in f32 D-layout (scan1's last step skips the exchange).

#define SEQ   8192
#define DIN   64
#define LCH   16
#define NCH   (SEQ / LCH)        // 512 chunks -> 2 blocks/CU
#define KCOMB 7                  // horizon = 7*16 = 112 steps (validated)

typedef _Float16 v8h __attribute__((ext_vector_type(8)));
typedef __fp16   v2h __attribute__((ext_vector_type(2)));
typedef float    v4f __attribute__((ext_vector_type(4)));

#define MFMA(a, b, c) __builtin_amdgcn_mfma_f32_16x16x32_f16((a), (b), (c), 0, 0, 0)
#define PKRTZ __builtin_amdgcn_cvt_pkrtz
#define Z4 (v4f{0.f, 0.f, 0.f, 0.f})

// F (f16 element offsets):
#define OFF_AH 0
#define OFF_AL 16384
#define OFF_BH 32768
#define OFF_BL 40960
#define OFF_CH 49152
#define OFF_CL 57344
#define OFF_TH 65536
#define OFF_TL 81920
// F end = 98304 f16 = 196608 B.  f32: Bbs @ byte 196608 (512 B);
// pw @ 197120 (4 slots x 65536 B: A2,A4,A8,A16); Vbuf f32 @ 459264
// ([512 chunks][256 tid][8] = 4 MiB).  Total ws = 4653568 B.

__device__ __forceinline__ int rho_fwd(int lidx) {
  int kt = lidx >> 5, q = (lidx >> 3) & 3, e = lidx & 7;
  int eh = e >> 1;
  int m = kt + 4 * (eh & 1);
  int r = 2 * (eh >> 1) + (e & 1);
  return 16 * m + 4 * q + r;
}
__device__ __forceinline__ int rho_inv(int p) {
  int m = p >> 4, q = (p >> 2) & 3, r = p & 3;
  int eh = ((r >> 1) << 1) | (m >> 2);
  int e  = (eh << 1) | (r & 1);
  return 32 * (m & 3) + 8 * q + e;
}
__device__ __forceinline__ void pack_hl(float v, _Float16* hp, _Float16* lp) {
  _Float16 h = (_Float16)v;
  *hp = h; *lp = (_Float16)(v - (float)h);
}

// one fp32 128x128x128 matmul; 4 partial sums break the dep chain.
__global__ void mmk(const float* __restrict__ X, const float* __restrict__ Y,
                    float* __restrict__ D) {
  int idx = blockIdx.x * 256 + threadIdx.x;
  int i = idx >> 7, j = idx & 127;
  const float* xr = X + i * 128;
  const float* yc = Y + j;
  float s0 = 0.f, s1 = 0.f, s2 = 0.f, s3 = 0.f;
#pragma unroll
  for (int k = 0; k < 128; k += 4) {
    s0 = fmaf(xr[k],     yc[(k)     * 128], s0);
    s1 = fmaf(xr[k + 1], yc[(k + 1) * 128], s1);
    s2 = fmaf(xr[k + 2], yc[(k + 2) * 128], s2);
    s3 = fmaf(xr[k + 3], yc[(k + 3) * 128], s3);
  }
  D[idx] = (s0 + s1) + (s2 + s3);
}

__global__ void packk(const float* __restrict__ A, const float* __restrict__ Bw,
                      const float* __restrict__ Bb, const float* __restrict__ Cw,
                      const float* __restrict__ A16, _Float16* __restrict__ F,
                      float* __restrict__ Bbs) {
  int idx = blockIdx.x * 256 + threadIdx.x;
  if (idx < 16384) {                       // A, rho rows
    int i = idx >> 7, j = idx & 127;
    int o = rho_fwd(i) * 128 + j;
    pack_hl(A[idx], F + OFF_AH + o, F + OFF_AL + o);
  } else if (idx < 24576) {                // Bw, rho rows
    int p = idx - 16384; int i = p >> 6, j = p & 63;
    int o = rho_fwd(i) * 64 + j;
    pack_hl(Bw[p], F + OFF_BH + o, F + OFF_BL + o);
  } else if (idx < 32768) {                // Cw plain
    int p = idx - 24576;
    pack_hl(Cw[p], F + OFF_CH + p, F + OFF_CL + p);
  } else if (idx < 32896) {                // Bbs rho
    int i = idx - 32768;
    Bbs[i] = Bb[rho_inv(i)];
  } else if (idx < 49280) {                // T = A^16, rho rows
    int p = idx - 32896; int i = p >> 7, j = p & 127;
    int o = rho_fwd(i) * 128 + j;
    pack_hl(A16[p], F + OFF_TH + o, F + OFF_TL + o);
  }
}

__device__ __forceinline__ void split16(const v4f* b, v8h& xh0, v8h& xh1,
                                        v8h& xl0, v8h& xl1) {
  union { v2h h2[4]; v8h h8; } H0, H1;
  H0.h2[0] = PKRTZ(b[0][0], b[0][1]); H0.h2[1] = PKRTZ(b[0][2], b[0][3]);
  H0.h2[2] = PKRTZ(b[1][0], b[1][1]); H0.h2[3] = PKRTZ(b[1][2], b[1][3]);
  H1.h2[0] = PKRTZ(b[2][0], b[2][1]); H1.h2[1] = PKRTZ(b[2][2], b[2][3]);
  H1.h2[2] = PKRTZ(b[3][0], b[3][1]); H1.h2[3] = PKRTZ(b[3][2], b[3][3]);
  float r[16];
#pragma unroll
  for (int i = 0; i < 8; ++i) r[i]     = b[i >> 2][i & 3]       - (float)H0.h8[i];
#pragma unroll
  for (int i = 0; i < 8; ++i) r[8 + i] = b[2 + (i >> 2)][i & 3] - (float)H1.h8[i];
  union { v2h h2[4]; v8h h8; } L0, L1;
  L0.h2[0] = PKRTZ(r[0], r[1]);   L0.h2[1] = PKRTZ(r[2], r[3]);
  L0.h2[2] = PKRTZ(r[4], r[5]);   L0.h2[3] = PKRTZ(r[6], r[7]);
  L1.h2[0] = PKRTZ(r[8], r[9]);   L1.h2[1] = PKRTZ(r[10], r[11]);
  L1.h2[2] = PKRTZ(r[12], r[13]); L1.h2[3] = PKRTZ(r[14], r[15]);
  xh0 = H0.h8; xh1 = H1.h8; xl0 = L0.h8; xl1 = L1.h8;
}

// ---------------- scan1: local chunk scan from h=0, store v_c (f32 D) -------
__global__ __launch_bounds__(256, 2) void scan1(
    const float* __restrict__ x, const _Float16* __restrict__ F,
    const float* __restrict__ Bbs, float* __restrict__ Vbuf) {
  const int tid = threadIdx.x;
  const int wv  = tid >> 6;
  const int l   = tid & 63;
  const int n   = l & 15;
  const int q   = l >> 4;
  const int c   = blockIdx.x;
  const int t0  = c * LCH;

  v8h afh[2][4], afl[2][4], bwh[2][2], bwl[2][2];
  v4f bb2[2];
#pragma unroll
  for (int i = 0; i < 2; ++i) {
    int row = 16 * (wv + 4 * i) + n;
#pragma unroll
    for (int kt = 0; kt < 4; ++kt) {
      afh[i][kt] = *(const v8h*)(F + OFF_AH + row * 128 + 32 * kt + 8 * q);
      afl[i][kt] = *(const v8h*)(F + OFF_AL + row * 128 + 32 * kt + 8 * q);
    }
#pragma unroll
    for (int k2 = 0; k2 < 2; ++k2) {
      bwh[i][k2] = *(const v8h*)(F + OFF_BH + row * 64 + 32 * k2 + 8 * q);
      bwl[i][k2] = *(const v8h*)(F + OFF_BL + row * 64 + 32 * k2 + 8 * q);
    }
    bb2[i] = *(const v4f*)(Bbs + 16 * (wv + 4 * i) + 4 * q);
  }

  __shared__ _Float16 hx[2][2][4][512];

  const float* xb = x + (size_t)n * (SEQ * DIN) + 8 * q;
  v4f bufA[4], bufB[4], uA[2], uB[2];
  auto loadx = [&](v4f(&buf)[4], int t) {
    const float* p = xb + (size_t)t * DIN;
    buf[0] = *(const v4f*)(p);      buf[1] = *(const v4f*)(p + 4);
    buf[2] = *(const v4f*)(p + 32); buf[3] = *(const v4f*)(p + 36);
  };
  auto build_u = [&](const v4f(&b)[4]) {
    v8h xh0, xh1, xl0, xl1;
    split16(b, xh0, xh1, xl0, xl1);
#pragma unroll
    for (int i = 0; i < 2; ++i) {
      v4f a = bb2[i];
      a = MFMA(bwh[i][0], xh0, a);
      a = MFMA(bwh[i][1], xh1, a);
      uA[i] = a;
      v4f b1 = MFMA(bwl[i][0], xh0, Z4);
      b1 = MFMA(bwl[i][1], xh1, b1);
      v4f b2 = MFMA(bwh[i][0], xl0, Z4);
      b2 = MFMA(bwh[i][1], xl1, b2);
      uB[i] = b1 + b2;
    }
  };
  auto xwrite = [&](int pr, const v4f& a0, const v4f& a1) {
    union { v2h h2[4]; v8h h8; } U;
    U.h2[0] = PKRTZ(a0[0], a0[1]); U.h2[1] = PKRTZ(a1[0], a1[1]);
    U.h2[2] = PKRTZ(a0[2], a0[3]); U.h2[3] = PKRTZ(a1[2], a1[3]);
    *(v8h*)&hx[pr][0][wv][l * 8] = U.h8;
    float r0 = a0[0] - (float)U.h8[0], r1 = a0[1] - (float)U.h8[1];
    float r2 = a1[0] - (float)U.h8[2], r3 = a1[1] - (float)U.h8[3];
    float r4 = a0[2] - (float)U.h8[4], r5 = a0[3] - (float)U.h8[5];
    float r6 = a1[2] - (float)U.h8[6], r7 = a1[3] - (float)U.h8[7];
    union { v2h h2[4]; v8h h8; } L;
    L.h2[0] = PKRTZ(r0, r1); L.h2[1] = PKRTZ(r2, r3);
    L.h2[2] = PKRTZ(r4, r5); L.h2[3] = PKRTZ(r6, r7);
    *(v8h*)&hx[pr][1][wv][l * 8] = L.h8;
  };

  v8h hf[4], hlo[4];
#pragma unroll
  for (int kt = 0; kt < 4; ++kt) { hf[kt] = v8h{}; hlo[kt] = v8h{}; }

  auto rec24 = [&](v4f(&acc)[2]) {
#pragma unroll
    for (int i = 0; i < 2; ++i) {
      v4f a = MFMA(afh[i][0], hf[0], uA[i]);
      a     = MFMA(afh[i][1], hf[1], a);
      v4f b = MFMA(afh[i][2], hf[2], Z4);
      b     = MFMA(afh[i][3], hf[3], b);
      v4f c2a = MFMA(afl[i][0], hf[0], uB[i]);
      c2a     = MFMA(afl[i][1], hf[1], c2a);
      v4f c2b = MFMA(afl[i][2], hf[2], Z4);
      c2b     = MFMA(afl[i][3], hf[3], c2b);
      v4f c3a = MFMA(afh[i][0], hlo[0], Z4);
      c3a     = MFMA(afh[i][1], hlo[1], c3a);
      v4f c3b = MFMA(afh[i][2], hlo[2], Z4);
      c3b     = MFMA(afh[i][3], hlo[3], c3b);
      acc[i] = (a + b) + (c2a + c2b) + (c3a + c3b);
    }
  };

  auto step = [&](int t, v4f(&bsrc)[4], v4f(&bld)[4], int pr) {
    int tn = t + 2; if (tn > SEQ - 1) tn = SEQ - 1;
    loadx(bld, tn);                        // EARLY issue: hides HBM under MFMA
    v4f acc[2];
    rec24(acc);
    build_u(bsrc);
    xwrite(pr, acc[0], acc[1]);
    __syncthreads();
#pragma unroll
    for (int kt = 0; kt < 4; ++kt) {
      hf[kt]  = *(const v8h*)&hx[pr][0][kt][l * 8];
      hlo[kt] = *(const v8h*)&hx[pr][1][kt][l * 8];
    }
  };

  loadx(bufA, t0);
  loadx(bufB, t0 + 1);
  build_u(bufA);
#pragma unroll
  for (int tp = 0; tp < 7; ++tp) {
    step(t0 + 2 * tp,     bufB, bufA, 0);
    step(t0 + 2 * tp + 1, bufA, bufB, 1);
  }
  step(t0 + 14, bufB, bufA, 0);
  // final step t0+15: no exchange needed; store v_c = acc (f32 D-layout)
  v4f acc[2];
  rec24(acc);
  float* vb = Vbuf + (size_t)c * 2048 + tid * 8;
  *(v4f*)vb       = acc[0];
  *(v4f*)(vb + 4) = acc[1];
}

// -------- scan2: Horner combine (T=A^16), then 16 emit steps ----------------
__global__ __launch_bounds__(256, 2) void scan2(
    const float* __restrict__ x, float* __restrict__ y,
    const _Float16* __restrict__ F, const float* __restrict__ Bbs,
    const float* __restrict__ Vbuf) {
  const int tid = threadIdx.x;
  const int wv  = tid >> 6;
  const int l   = tid & 63;
  const int n   = l & 15;
  const int q   = l >> 4;
  const int c   = blockIdx.x;
  const int t0  = c * LCH, te = t0 + LCH;

  __shared__ _Float16 hx[2][2][4][512];

  const float* xb = x + (size_t)n * (SEQ * DIN) + 8 * q;
  float* yb = y + (size_t)n * (SEQ * DIN);
  v4f bufA[4], bufB[4];
  auto loadx = [&](v4f(&buf)[4], int t) {
    const float* p = xb + (size_t)t * DIN;
    buf[0] = *(const v4f*)(p);      buf[1] = *(const v4f*)(p + 4);
    buf[2] = *(const v4f*)(p + 32); buf[3] = *(const v4f*)(p + 36);
  };
  loadx(bufA, t0);                 // issue phase-B x now; hides under combine
  loadx(bufB, t0 + 1);

  v8h afh[2][4], afl[2][4];        // shared by T (phase A) then A (phase B)
  auto load_AF = [&](int oh, int ol) {
#pragma unroll
    for (int i = 0; i < 2; ++i) {
      int row = 16 * (wv + 4 * i) + n;
#pragma unroll
      for (int kt = 0; kt < 4; ++kt) {
        afh[i][kt] = *(const v8h*)(F + oh + row * 128 + 32 * kt + 8 * q);
        afl[i][kt] = *(const v8h*)(F + ol + row * 128 + 32 * kt + 8 * q);
      }
    }
  };

  auto xwrite = [&](int pr, const v4f& a0, const v4f& a1) {
    union { v2h h2[4]; v8h h8; } U;
    U.h2[0] = PKRTZ(a0[0], a0[1]); U.h2[1] = PKRTZ(a1[0], a1[1]);
    U.h2[2] = PKRTZ(a0[2], a0[3]); U.h2[3] = PKRTZ(a1[2], a1[3]);
    *(v8h*)&hx[pr][0][wv][l * 8] = U.h8;
    float r0 = a0[0] - (float)U.h8[0], r1 = a0[1] - (float)U.h8[1];
    float r2 = a1[0] - (float)U.h8[2], r3 = a1[1] - (float)U.h8[3];
    float r4 = a0[2] - (float)U.h8[4], r5 = a0[3] - (float)U.h8[5];
    float r6 = a1[2] - (float)U.h8[6], r7 = a1[3] - (float)U.h8[7];
    union { v2h h2[4]; v8h h8; } L;
    L.h2[0] = PKRTZ(r0, r1); L.h2[1] = PKRTZ(r2, r3);
    L.h2[2] = PKRTZ(r4, r5); L.h2[3] = PKRTZ(r6, r7);
    *(v8h*)&hx[pr][1][wv][l * 8] = L.h8;
  };

  v8h hf[4], hlo[4];
#pragma unroll
  for (int kt = 0; kt < 4; ++kt) { hf[kt] = v8h{}; hlo[kt] = v8h{}; }

  int pr = 0;

  // ---- phase A: Horner combine  s <- T s + v_{c-kk},  kk = kmax..1
  if (c > 0) {
    load_AF(OFF_TH, OFF_TL);
    const int kmax = (c < KCOMB) ? c : KCOMB;
    const float* vp = Vbuf + (size_t)(c - kmax) * 2048 + tid * 8;
    v4f v0 = *(const v4f*)vp, v1 = *(const v4f*)(vp + 4);
    for (int kk = kmax; kk >= 1; --kk) {
      v4f vc0 = v0, vc1 = v1;
      if (kk > 1) {                        // prefetch next level's v
        const float* vn = Vbuf + (size_t)(c - kk + 1) * 2048 + tid * 8;
        v0 = *(const v4f*)vn; v1 = *(const v4f*)(vn + 4);
      }
      v4f acc[2];
#pragma unroll
      for (int i = 0; i < 2; ++i) {
        v4f ui = (i == 0) ? vc0 : vc1;
        v4f a = MFMA(afh[i][0], hf[0], ui);
        a     = MFMA(afh[i][1], hf[1], a);
        v4f b = MFMA(afh[i][2], hf[2], Z4);
        b     = MFMA(afh[i][3], hf[3], b);
        v4f c2a = MFMA(afl[i][0], hf[0], Z4);
        c2a     = MFMA(afl[i][1], hf[1], c2a);
        v4f c2b = MFMA(afl[i][2], hf[2], Z4);
        c2b     = MFMA(afl[i][3], hf[3], c2b);
        v4f c3a = MFMA(afh[i][0], hlo[0], Z4);
        c3a     = MFMA(afh[i][1], hlo[1], c3a);
        v4f c3b = MFMA(afh[i][2], hlo[2], Z4);
        c3b     = MFMA(afh[i][3], hlo[3], c3b);
        acc[i] = (a + b) + (c2a + c2b) + (c3a + c3b);
      }
      xwrite(pr, acc[0], acc[1]);
      __syncthreads();
#pragma unroll
      for (int kt = 0; kt < 4; ++kt) {
        hf[kt]  = *(const v8h*)&hx[pr][0][kt][l * 8];
        hlo[kt] = *(const v8h*)&hx[pr][1][kt][l * 8];
      }
      pr ^= 1;
    }
  }
  load_AF(OFF_AH, OFF_AL);                 // phase B: A into the same regs

  v8h bwh[2][2], bwl[2][2], cwh[4], cwl[4];
  v4f bb2[2];
#pragma unroll
  for (int i = 0; i < 2; ++i) {
    int row = 16 * (wv + 4 * i) + n;
#pragma unroll
    for (int k2 = 0; k2 < 2; ++k2) {
      bwh[i][k2] = *(const v8h*)(F + OFF_BH + row * 64 + 32 * k2 + 8 * q);
      bwl[i][k2] = *(const v8h*)(F + OFF_BL + row * 64 + 32 * k2 + 8 * q);
    }
    bb2[i] = *(const v4f*)(Bbs + 16 * (wv + 4 * i) + 4 * q);
  }
  {
    int row = 16 * wv + n;
#pragma unroll
    for (int kt = 0; kt < 4; ++kt) {
      cwh[kt] = *(const v8h*)(F + OFF_CH + row * 128 + 32 * kt + 8 * q);
      cwl[kt] = *(const v8h*)(F + OFF_CL + row * 128 + 32 * kt + 8 * q);
    }
  }

  v4f uA[2], uB[2];
  auto build_u = [&](const v4f(&b)[4]) {
    v8h xh0, xh1, xl0, xl1;
    split16(b, xh0, xh1, xl0, xl1);
#pragma unroll
    for (int i = 0; i < 2; ++i) {
      v4f a = bb2[i];
      a = MFMA(bwh[i][0], xh0, a);
      a = MFMA(bwh[i][1], xh1, a);
      uA[i] = a;
      v4f b1 = MFMA(bwl[i][0], xh0, Z4);
      b1 = MFMA(bwl[i][1], xh1, b1);
      v4f b2 = MFMA(bwh[i][0], xl0, Z4);
      b2 = MFMA(bwh[i][1], xl1, b2);
      uB[i] = b1 + b2;
    }
  };
  auto emit_y = [&](int t) {
    v4f e1a = MFMA(cwh[1], hf[1], MFMA(cwh[0], hf[0], Z4));
    v4f e1b = MFMA(cwh[3], hf[3], MFMA(cwh[2], hf[2], Z4));
    v4f e2a = MFMA(cwh[1], hlo[1], MFMA(cwh[0], hlo[0], Z4));
    v4f e2b = MFMA(cwh[3], hlo[3], MFMA(cwh[2], hlo[2], Z4));
    v4f e3a = MFMA(cwl[1], hf[1], MFMA(cwl[0], hf[0], Z4));
    v4f e3b = MFMA(cwl[3], hf[3], MFMA(cwl[2], hf[2], Z4));
    v4f r = (e1a + e1b) + (e2a + e2b) + (e3a + e3b);
    *(v4f*)(yb + (size_t)t * DIN + 16 * wv + 4 * q) = r;
  };
  auto stepE = [&](int t, v4f(&bsrc)[4], v4f(&bld)[4], bool emit) {
    int tn = t + 2; if (tn > SEQ - 1) tn = SEQ - 1;
    loadx(bld, tn);                        // EARLY issue
    if (emit) emit_y(t - 1);
    v4f acc[2];
#pragma unroll
    for (int i = 0; i < 2; ++i) {
      v4f a = MFMA(afh[i][0], hf[0], uA[i]);
      a     = MFMA(afh[i][1], hf[1], a);
      v4f b = MFMA(afh[i][2], hf[2], Z4);
      b     = MFMA(afh[i][3], hf[3], b);
      v4f c2a = MFMA(afl[i][0], hf[0], uB[i]);
      c2a     = MFMA(afl[i][1], hf[1], c2a);
      v4f c2b = MFMA(afl[i][2], hf[2], Z4);
      c2b     = MFMA(afl[i][3], hf[3], c2b);
      v4f c3a = MFMA(afh[i][0], hlo[0], Z4);
      c3a     = MFMA(afh[i][1], hlo[1], c3a);
      v4f c3b = MFMA(afh[i][2], hlo[2], Z4);
      c3b     = MFMA(afh[i][3], hlo[3], c3b);
      acc[i] = (a + b) + (c2a + c2b) + (c3a + c3b);
    }
    build_u(bsrc);
    xwrite(pr, acc[0], acc[1]);
    __syncthreads();
#pragma unroll
    for (int kt = 0; kt < 4; ++kt) {
      hf[kt]  = *(const v8h*)&hx[pr][0][kt][l * 8];
      hlo[kt] = *(const v8h*)&hx[pr][1][kt][l * 8];
    }
    pr ^= 1;
  };

  build_u(bufA);                           // u(t0); x long since arrived
#pragma unroll
  for (int tp = 0; tp < 8; ++tp) {
    stepE(t0 + 2 * tp,     bufB, bufA, tp > 0);
    stepE(t0 + 2 * tp + 1, bufA, bufB, true);
  }
  emit_y(te - 1);
}

extern "C" void kernel_launch(void* const* d_in, const int* in_sizes, int n_in,
                              void* d_out, int out_size, void* d_ws, size_t ws_size,
                              hipStream_t stream) {
  const float* x  = (const float*)d_in[0];
  const float* A  = (const float*)d_in[1];
  const float* Bw = (const float*)d_in[2];
  const float* Bb = (const float*)d_in[3];
  const float* Cw = (const float*)d_in[4];
  float* y = (float*)d_out;

  _Float16* F    = (_Float16*)d_ws;                     // 196608 B
  float*    Bbs  = (float*)((char*)d_ws + 196608);      // 512 B
  float*    pw   = (float*)((char*)d_ws + 197120);      // 4*65536 B
  float*    Vbuf = (float*)((char*)d_ws + 459264);      // 4 MiB (total 4653568 B)

  float* A2  = pw;
  float* A4  = pw + 16384;
  float* A8  = pw + 32768;
  float* A16 = pw + 49152;

  mmk<<<64, 256, 0, stream>>>(A,  A,  A2);
  mmk<<<64, 256, 0, stream>>>(A2, A2, A4);
  mmk<<<64, 256, 0, stream>>>(A4, A4, A8);
  mmk<<<64, 256, 0, stream>>>(A8, A8, A16);
  packk<<<193, 256, 0, stream>>>(A, Bw, Bb, Cw, A16, F, Bbs);
  scan1<<<NCH, 256, 0, stream>>>(x, F, Bbs, Vbuf);
  scan2<<<NCH, 256, 0, stream>>>(x, y, F, Bbs, Vbuf);
}